// Round 1
// baseline (265.667 us; speedup 1.0000x reference)
//
#include <hip/hip_runtime.h>
#include <hip/hip_bf16.h>
#include <cstdint>
#include <cstddef>

// ---------------------------------------------------------------------------
// MultiHeadAttention (B=2, S=2048, D=1024, H=16, DK=64), fp32 in/out,
// bf16 MFMA internal compute.
// Pipeline: cvt(fp32->bf16) -> 3x GEMM proj -> flash attention -> GEMM out.
// ---------------------------------------------------------------------------

#define B_ 2
#define S_ 2048
#define D_ 1024
#define H_ 16
#define DK_ 64

typedef __attribute__((ext_vector_type(8))) short bf16x8;
typedef __attribute__((ext_vector_type(4))) float f32x4;
typedef __attribute__((ext_vector_type(8))) unsigned short u16x8;
typedef __attribute__((ext_vector_type(4))) unsigned short u16x4;
typedef __attribute__((ext_vector_type(4))) float float4v;

__device__ __forceinline__ unsigned short f2bf(float f) {
  unsigned int u = __float_as_uint(f);
  u += 0x7FFFu + ((u >> 16) & 1u);   // round-to-nearest-even
  return (unsigned short)(u >> 16);
}

// ---------------------------- fp32 -> bf16 convert -------------------------
__global__ __launch_bounds__(256) void cvt_f32_bf16(const float* __restrict__ src,
                                                    unsigned short* __restrict__ dst,
                                                    int n4) {
  int i = blockIdx.x * 256 + threadIdx.x;
  if (i < n4) {
    float4v v = *(const float4v*)(src + (size_t)i * 4);
    u16x4 o;
    o[0] = f2bf(v[0]); o[1] = f2bf(v[1]); o[2] = f2bf(v[2]); o[3] = f2bf(v[3]);
    *(u16x4*)(dst + (size_t)i * 4) = o;
  }
}

// ---------------------------- bf16 NT GEMM ---------------------------------
// C[M,N] = A[M,K] * W[N,K]^T + bias[N]; A,W bf16 row-major (K contiguous).
// 128x128 tile, BK=64, 256 threads = 4 waves (2x2), each wave 64x64 (4x4 frags).
template <int OUTF32>
__global__ __launch_bounds__(256) void gemm_nt(const unsigned short* __restrict__ A,
                                               const unsigned short* __restrict__ W,
                                               const float* __restrict__ bias,
                                               void* __restrict__ Cout,
                                               int M, int N, int K) {
  __shared__ unsigned short As[128 * 64];
  __shared__ unsigned short Bs[128 * 64];
  const int tid  = threadIdx.x;
  const int lane = tid & 63;
  const int m0 = blockIdx.x * 128;
  const int n0 = blockIdx.y * 128;
  const int wr = ((tid >> 6) >> 1) * 64;
  const int wc = ((tid >> 6) & 1) * 64;
  const int lr = lane & 15;         // frag row (A) / col (B,D)
  const int lk = (lane >> 4) * 8;   // frag k offset
  f32x4 acc[4][4] = {};

  const int chunkrow = tid >> 3;        // 0..31 (+32 per i)
  const int chunkcol = (tid & 7) * 8;   // ushort offset within 64-elem row

  for (int k0 = 0; k0 < K; k0 += 64) {
    __syncthreads();
#pragma unroll
    for (int i = 0; i < 4; ++i) {
      int row = chunkrow + i * 32;
      const unsigned short* gA = A + (size_t)(m0 + row) * K + k0 + chunkcol;
      const unsigned short* gB = W + (size_t)(n0 + row) * K + k0 + chunkcol;
      unsigned short* lA = As + row * 64 + chunkcol;
      unsigned short* lB = Bs + row * 64 + chunkcol;
      __builtin_amdgcn_global_load_lds((const __attribute__((address_space(1))) void*)gA,
                                       (__attribute__((address_space(3))) void*)lA, 16, 0, 0);
      __builtin_amdgcn_global_load_lds((const __attribute__((address_space(1))) void*)gB,
                                       (__attribute__((address_space(3))) void*)lB, 16, 0, 0);
    }
    __syncthreads();
#pragma unroll
    for (int kk = 0; kk < 2; ++kk) {
      bf16x8 a[4], b[4];
#pragma unroll
      for (int m = 0; m < 4; ++m)
        a[m] = *(const bf16x8*)(As + (wr + m * 16 + lr) * 64 + kk * 32 + lk);
#pragma unroll
      for (int n = 0; n < 4; ++n)
        b[n] = *(const bf16x8*)(Bs + (wc + n * 16 + lr) * 64 + kk * 32 + lk);
#pragma unroll
      for (int m = 0; m < 4; ++m)
#pragma unroll
        for (int n = 0; n < 4; ++n)
          acc[m][n] = __builtin_amdgcn_mfma_f32_16x16x32_bf16(a[m], b[n], acc[m][n], 0, 0, 0);
    }
  }

  const int rbase = (lane >> 4) * 4;
#pragma unroll
  for (int m = 0; m < 4; ++m) {
#pragma unroll
    for (int n = 0; n < 4; ++n) {
      int col = n0 + wc + n * 16 + lr;
      float bv = bias[col];
#pragma unroll
      for (int r = 0; r < 4; ++r) {
        int row = m0 + wr + m * 16 + rbase + r;
        float vv = acc[m][n][r] + bv;
        if (OUTF32)
          ((float*)Cout)[(size_t)row * N + col] = vv;
        else
          ((unsigned short*)Cout)[(size_t)row * N + col] = f2bf(vv);
      }
    }
  }
}

// ---------------------------- flash attention ------------------------------
// Grid: (S/64, H, B). 256 threads = 4 waves; wave w owns q rows [q0+16w, +16).
// K/V tiles 64 rows staged in LDS (stride 72 to break bank conflicts).
__global__ __launch_bounds__(256) void flash_attn(const unsigned short* __restrict__ Qp,
                                                  const unsigned short* __restrict__ Kp,
                                                  const unsigned short* __restrict__ Vp,
                                                  unsigned short* __restrict__ Op) {
  __shared__ unsigned short Ks[64][72];   // [kv][d]
  __shared__ unsigned short Vt[64][72];   // [d][kv] (transposed)
  __shared__ unsigned short Ps[4][16][72];// per-wave P tile [q][kv]

  const int tid  = threadIdx.x;
  const int lane = tid & 63;
  const int w = tid >> 6;
  const int q0 = blockIdx.x * 64;
  const int h  = blockIdx.y;
  const int b  = blockIdx.z;
  const int qw = q0 + w * 16;
  const int lr = lane & 15;
  const int lk = (lane >> 4) * 8;
  const int rbase = (lane >> 4) * 4;
  const size_t basebs = (size_t)b * S_ * D_;
  const int hoff = h * DK_;

  // Q fragments, kept in registers for the whole kv loop
  bf16x8 qf[2];
  {
    const unsigned short* qrow = Qp + basebs + (size_t)(qw + lr) * D_ + hoff;
    qf[0] = *(const bf16x8*)(qrow + lk);
    qf[1] = *(const bf16x8*)(qrow + 32 + lk);
  }

  float mold[4] = {-1e30f, -1e30f, -1e30f, -1e30f};
  float l[4] = {0.f, 0.f, 0.f, 0.f};
  f32x4 out[4] = {};

  const int ntiles = q0 / 64 + 1;   // causal: kv tiles 0..q0/64
  for (int t = 0; t < ntiles; ++t) {
    const int kv0 = t * 64;
    __syncthreads();
    {
      // stage K row-major and V transposed
      int r = tid >> 2, cc = (tid & 3) * 16;
      const unsigned short* gk = Kp + basebs + (size_t)(kv0 + r) * D_ + hoff + cc;
      *(bf16x8*)&Ks[r][cc]     = *(const bf16x8*)gk;
      *(bf16x8*)&Ks[r][cc + 8] = *(const bf16x8*)(gk + 8);
      const unsigned short* gv = Vp + basebs + (size_t)(kv0 + r) * D_ + hoff + cc;
      u16x8 v0 = *(const u16x8*)gv;
      u16x8 v1 = *(const u16x8*)(gv + 8);
#pragma unroll
      for (int i = 0; i < 8; ++i) Vt[cc + i][r] = v0[i];
#pragma unroll
      for (int i = 0; i < 8; ++i) Vt[cc + 8 + i][r] = v1[i];
    }
    __syncthreads();

    // scores: S = Q * K^T   (D row = q, D col = kv)
    f32x4 sc[4] = {};
#pragma unroll
    for (int kk = 0; kk < 2; ++kk) {
#pragma unroll
      for (int j = 0; j < 4; ++j) {
        bf16x8 kb = *(const bf16x8*)&Ks[j * 16 + lr][kk * 32 + lk];
        sc[j] = __builtin_amdgcn_mfma_f32_16x16x32_bf16(qf[kk], kb, sc[j], 0, 0, 0);
      }
    }

    const bool lastt = (kv0 == q0);
    float sv[4][4];
#pragma unroll
    for (int j = 0; j < 4; ++j)
#pragma unroll
      for (int r = 0; r < 4; ++r) {
        float s = sc[j][r] * 0.125f;  // 1/sqrt(64)
        if (lastt && (kv0 + j * 16 + lr) > (qw + rbase + r)) s = -1e30f;
        sv[j][r] = s;
      }

    // online softmax (row stats across 16-lane groups)
#pragma unroll
    for (int r = 0; r < 4; ++r) {
      float tm = fmaxf(fmaxf(sv[0][r], sv[1][r]), fmaxf(sv[2][r], sv[3][r]));
      tm = fmaxf(tm, __shfl_xor(tm, 1));
      tm = fmaxf(tm, __shfl_xor(tm, 2));
      tm = fmaxf(tm, __shfl_xor(tm, 4));
      tm = fmaxf(tm, __shfl_xor(tm, 8));
      float mnew = fmaxf(mold[r], tm);
      float scl = __expf(mold[r] - mnew);
      float ps = 0.f;
#pragma unroll
      for (int j = 0; j < 4; ++j) {
        float p = __expf(sv[j][r] - mnew);
        sv[j][r] = p;
        ps += p;
      }
      ps += __shfl_xor(ps, 1);
      ps += __shfl_xor(ps, 2);
      ps += __shfl_xor(ps, 4);
      ps += __shfl_xor(ps, 8);
      l[r] = l[r] * scl + ps;
      mold[r] = mnew;
#pragma unroll
      for (int j = 0; j < 4; ++j) out[j][r] *= scl;
    }

    // P -> LDS (re-layout to MFMA A-fragment)
#pragma unroll
    for (int r = 0; r < 4; ++r)
#pragma unroll
      for (int j = 0; j < 4; ++j)
        Ps[w][rbase + r][j * 16 + lr] = f2bf(sv[j][r]);
    __syncthreads();

    // PV: out += P(16x64) * V(64x64)
#pragma unroll
    for (int kk = 0; kk < 2; ++kk) {
      bf16x8 pa = *(const bf16x8*)&Ps[w][lr][kk * 32 + lk];
#pragma unroll
      for (int j = 0; j < 4; ++j) {
        bf16x8 vb = *(const bf16x8*)&Vt[j * 16 + lr][kk * 32 + lk];
        out[j] = __builtin_amdgcn_mfma_f32_16x16x32_bf16(pa, vb, out[j], 0, 0, 0);
      }
    }
  }

  // normalize + store (bf16)
#pragma unroll
  for (int r = 0; r < 4; ++r) {
    float rcp = 1.0f / l[r];
#pragma unroll
    for (int j = 0; j < 4; ++j) {
      size_t idx = basebs + (size_t)(qw + rbase + r) * D_ + hoff + j * 16 + lr;
      Op[idx] = f2bf(out[j][r] * rcp);
    }
  }
}

// ---------------------------- launch ---------------------------------------
extern "C" void kernel_launch(void* const* d_in, const int* in_sizes, int n_in,
                              void* d_out, int out_size, void* d_ws, size_t ws_size,
                              hipStream_t stream) {
  const float* q  = (const float*)d_in[0];
  const float* k  = (const float*)d_in[1];
  const float* v  = (const float*)d_in[2];
  // d_in[3] = causal mask (tril) -- semantics hard-coded in flash_attn
  const float* Wq = (const float*)d_in[4];
  const float* bq = (const float*)d_in[5];
  const float* Wk = (const float*)d_in[6];
  const float* bk = (const float*)d_in[7];
  const float* Wv = (const float*)d_in[8];
  const float* bv = (const float*)d_in[9];
  const float* Wo = (const float*)d_in[10];
  const float* bo = (const float*)d_in[11];

  const int MSD = B_ * S_;     // 4096 rows
  unsigned short* ws = (unsigned short*)d_ws;
  unsigned short* Xq  = ws;
  unsigned short* Xk  = Xq  + (size_t)MSD * D_;
  unsigned short* Xv  = Xk  + (size_t)MSD * D_;
  unsigned short* Wqb = Xv  + (size_t)MSD * D_;
  unsigned short* Wkb = Wqb + (size_t)D_ * D_;
  unsigned short* Wvb = Wkb + (size_t)D_ * D_;
  unsigned short* Wob = Wvb + (size_t)D_ * D_;
  unsigned short* Qp  = Wob + (size_t)D_ * D_;
  unsigned short* Kp  = Qp  + (size_t)MSD * D_;
  unsigned short* Vp  = Kp  + (size_t)MSD * D_;
  unsigned short* At  = Vp  + (size_t)MSD * D_;

  const int n4a = MSD * D_ / 4;   // 1048576
  const int n4w = D_ * D_ / 4;    // 262144
  cvt_f32_bf16<<<n4a / 256, 256, 0, stream>>>(q,  Xq,  n4a);
  cvt_f32_bf16<<<n4a / 256, 256, 0, stream>>>(k,  Xk,  n4a);
  cvt_f32_bf16<<<n4a / 256, 256, 0, stream>>>(v,  Xv,  n4a);
  cvt_f32_bf16<<<n4w / 256, 256, 0, stream>>>(Wq, Wqb, n4w);
  cvt_f32_bf16<<<n4w / 256, 256, 0, stream>>>(Wk, Wkb, n4w);
  cvt_f32_bf16<<<n4w / 256, 256, 0, stream>>>(Wv, Wvb, n4w);
  cvt_f32_bf16<<<n4w / 256, 256, 0, stream>>>(Wo, Wob, n4w);

  dim3 gg(MSD / 128, D_ / 128);   // (32, 8)
  gemm_nt<0><<<gg, 256, 0, stream>>>(Xq, Wqb, bq, Qp, MSD, D_, D_);
  gemm_nt<0><<<gg, 256, 0, stream>>>(Xk, Wkb, bk, Kp, MSD, D_, D_);
  gemm_nt<0><<<gg, 256, 0, stream>>>(Xv, Wvb, bv, Vp, MSD, D_, D_);

  dim3 ga(S_ / 64, H_, B_);       // (32, 16, 2)
  flash_attn<<<ga, 256, 0, stream>>>(Qp, Kp, Vp, At);

  gemm_nt<1><<<gg, 256, 0, stream>>>(At, Wob, bo, d_out, MSD, D_, D_);
}

// Round 2
// 251.869 us; speedup vs baseline: 1.0548x; 1.0548x over previous
//
#include <hip/hip_runtime.h>
#include <hip/hip_bf16.h>
#include <cstdint>
#include <cstddef>

// ---------------------------------------------------------------------------
// MultiHeadAttention (B=2, S=2048, D=1024, H=16, DK=64), fp32 in/out,
// bf16 MFMA internal compute.
// cvt -> Q/K GEMM (Q pre-scaled by 1/8), V GEMM (writes V^T per head)
//     -> flash attention (global_load_lds + XOR swizzle, 2-phase dbuf)
//     -> O GEMM (fp32 out)
// ---------------------------------------------------------------------------

#define B_ 2
#define S_ 2048
#define D_ 1024
#define H_ 16
#define DK_ 64

typedef __attribute__((ext_vector_type(8))) short bf16x8;
typedef __attribute__((ext_vector_type(4))) float f32x4;
typedef __attribute__((ext_vector_type(4))) unsigned short u16x4;
typedef __attribute__((ext_vector_type(4))) float float4v;

__device__ __forceinline__ unsigned short f2bf(float f) {
  unsigned int u = __float_as_uint(f);
  u += 0x7FFFu + ((u >> 16) & 1u);   // round-to-nearest-even
  return (unsigned short)(u >> 16);
}

// ---------------------------- fp32 -> bf16 convert -------------------------
__global__ __launch_bounds__(256) void cvt_f32_bf16(const float* __restrict__ src,
                                                    unsigned short* __restrict__ dst,
                                                    int n4) {
  int i = blockIdx.x * 256 + threadIdx.x;
  if (i < n4) {
    float4v v = *(const float4v*)(src + (size_t)i * 4);
    u16x4 o;
    o[0] = f2bf(v[0]); o[1] = f2bf(v[1]); o[2] = f2bf(v[2]); o[3] = f2bf(v[3]);
    *(u16x4*)(dst + (size_t)i * 4) = o;
  }
}

// ---------------------------- bf16 NT GEMM ---------------------------------
// C[M,N] = (A[M,K] * W[N,K]^T + bias[N]) * scale
// MODE 0: bf16 row-major out.  MODE 1: fp32 row-major out.
// MODE 2: bf16 out transposed per head: Vt[b][h][dk][s]  (col=(h,dk), row=(b,s))
template <int MODE>
__global__ __launch_bounds__(256) void gemm_nt(const unsigned short* __restrict__ A,
                                               const unsigned short* __restrict__ W,
                                               const float* __restrict__ bias,
                                               void* __restrict__ Cout,
                                               int M, int N, int K, float scale) {
  __shared__ unsigned short As[128 * 64];
  __shared__ unsigned short Bs[128 * 64];
  const int tid  = threadIdx.x;
  const int lane = tid & 63;
  const int m0 = blockIdx.x * 128;
  const int n0 = blockIdx.y * 128;
  const int wr = ((tid >> 6) >> 1) * 64;
  const int wc = ((tid >> 6) & 1) * 64;
  const int lr = lane & 15;
  const int lk = (lane >> 4) * 8;
  f32x4 acc[4][4] = {};

  const int chunkrow = tid >> 3;
  const int chunkcol = (tid & 7) * 8;

  for (int k0 = 0; k0 < K; k0 += 64) {
    __syncthreads();
#pragma unroll
    for (int i = 0; i < 4; ++i) {
      int row = chunkrow + i * 32;
      const unsigned short* gA = A + (size_t)(m0 + row) * K + k0 + chunkcol;
      const unsigned short* gB = W + (size_t)(n0 + row) * K + k0 + chunkcol;
      unsigned short* lA = As + row * 64 + chunkcol;
      unsigned short* lB = Bs + row * 64 + chunkcol;
      __builtin_amdgcn_global_load_lds((const __attribute__((address_space(1))) void*)gA,
                                       (__attribute__((address_space(3))) void*)lA, 16, 0, 0);
      __builtin_amdgcn_global_load_lds((const __attribute__((address_space(1))) void*)gB,
                                       (__attribute__((address_space(3))) void*)lB, 16, 0, 0);
    }
    __syncthreads();
#pragma unroll
    for (int kk = 0; kk < 2; ++kk) {
      bf16x8 a[4], b[4];
#pragma unroll
      for (int m = 0; m < 4; ++m)
        a[m] = *(const bf16x8*)(As + (wr + m * 16 + lr) * 64 + kk * 32 + lk);
#pragma unroll
      for (int n = 0; n < 4; ++n)
        b[n] = *(const bf16x8*)(Bs + (wc + n * 16 + lr) * 64 + kk * 32 + lk);
#pragma unroll
      for (int m = 0; m < 4; ++m)
#pragma unroll
        for (int n = 0; n < 4; ++n)
          acc[m][n] = __builtin_amdgcn_mfma_f32_16x16x32_bf16(a[m], b[n], acc[m][n], 0, 0, 0);
    }
  }

  const int rbase = (lane >> 4) * 4;
#pragma unroll
  for (int m = 0; m < 4; ++m) {
#pragma unroll
    for (int n = 0; n < 4; ++n) {
      int col = n0 + wc + n * 16 + lr;
      float bv = bias[col];
      if (MODE == 2) {
        // transposed per-head store: 4 consecutive s for fixed d -> u16x4
        int row0 = m0 + wr + m * 16 + rbase;
        int bb = row0 >> 11, s = row0 & 2047;
        int h = col >> 6, dk = col & 63;
        u16x4 o;
#pragma unroll
        for (int r = 0; r < 4; ++r) o[r] = f2bf((acc[m][n][r] + bv) * scale);
        size_t idx = (((size_t)bb * H_ + h) * DK_ + dk) * S_ + s;
        *(u16x4*)((unsigned short*)Cout + idx) = o;
      } else {
#pragma unroll
        for (int r = 0; r < 4; ++r) {
          int row = m0 + wr + m * 16 + rbase + r;
          float vv = (acc[m][n][r] + bv) * scale;
          if (MODE == 1)
            ((float*)Cout)[(size_t)row * N + col] = vv;
          else
            ((unsigned short*)Cout)[(size_t)row * N + col] = f2bf(vv);
        }
      }
    }
  }
}

// ---------------------------- flash attention ------------------------------
// Grid: (S/64, H, B). 256 threads = 4 waves; wave w owns q rows [q0+16w,+16).
// K tile [kv][d] and V^T tile [d][kv] staged via global_load_lds into
// XOR-swizzled LDS (byte ^= ((row&7)<<4)); 2-phase double buffer.
__device__ __forceinline__ void stage_tile(const unsigned short* __restrict__ gK,
                                           const unsigned short* __restrict__ gV,
                                           unsigned short* kb, unsigned short* vb,
                                           int tid) {
  const int w = tid >> 6, l = tid & 63;
#pragma unroll
  for (int i = 0; i < 2; ++i) {
    int X = w * 2048 + i * 1024 + l * 16;     // dest byte (linear, lane-ordered)
    int P = X ^ (((X >> 7) & 7) << 4);        // logical byte (pre-swizzled src)
    int row = P >> 7;
    int colu = (P & 127) >> 1;                // ushort col within 64-wide row
    __builtin_amdgcn_global_load_lds(
        (const __attribute__((address_space(1))) void*)(gK + (size_t)row * D_ + colu),
        (__attribute__((address_space(3))) void*)((char*)kb + X), 16, 0, 0);
    __builtin_amdgcn_global_load_lds(
        (const __attribute__((address_space(1))) void*)(gV + (size_t)row * S_ + colu),
        (__attribute__((address_space(3))) void*)((char*)vb + X), 16, 0, 0);
  }
}

__device__ __forceinline__ bf16x8 lds_read_sw(const unsigned short* base, int row, int col) {
  int P = (row * 64 + col) * 2;
  int X = P ^ ((row & 7) << 4);
  return *(const bf16x8*)((const char*)base + X);
}

__global__ __launch_bounds__(256) void flash_attn(const unsigned short* __restrict__ Qp,
                                                  const unsigned short* __restrict__ Kp,
                                                  const unsigned short* __restrict__ Vtp,
                                                  unsigned short* __restrict__ Op) {
  __shared__ unsigned short Kb[2][4096];
  __shared__ unsigned short Vb[2][4096];
  __shared__ unsigned short Ps[4][16 * 72];

  const int tid  = threadIdx.x;
  const int lane = tid & 63;
  const int w = tid >> 6;
  const int bx = blockIdx.x;
  const int qt = (bx & 1) ? (31 - (bx >> 1)) : (bx >> 1);  // causal load pairing
  const int q0 = qt * 64;
  const int h  = blockIdx.y;
  const int b  = blockIdx.z;
  const int qw = q0 + w * 16;
  const int lr = lane & 15;
  const int lk = (lane >> 4) * 8;
  const int rbase = (lane >> 4) * 4;
  const size_t basebs = (size_t)b * S_ * D_;
  const int hoff = h * DK_;

  // Q fragments (Q already scaled by 1/sqrt(dk) in the Q-GEMM epilogue)
  bf16x8 qf[2];
  {
    const unsigned short* qrow = Qp + basebs + (size_t)(qw + lr) * D_ + hoff;
    qf[0] = *(const bf16x8*)(qrow + lk);
    qf[1] = *(const bf16x8*)(qrow + 32 + lk);
  }

  float mold[4] = {-1e30f, -1e30f, -1e30f, -1e30f};
  float l[4] = {0.f, 0.f, 0.f, 0.f};
  f32x4 out[4] = {};

  const unsigned short* gK0 = Kp + basebs + hoff;                       // +kv0*D_
  const unsigned short* gV0 = Vtp + ((size_t)b * H_ + h) * DK_ * S_;    // +kv0 col

  const int ntiles = q0 / 64 + 1;
  stage_tile(gK0, gV0, Kb[0], Vb[0], tid);
  __syncthreads();

  for (int t = 0; t < ntiles; ++t) {
    const int cur = t & 1;
    if (t + 1 < ntiles)
      stage_tile(gK0 + (size_t)(t + 1) * 64 * D_, gV0 + (t + 1) * 64,
                 Kb[cur ^ 1], Vb[cur ^ 1], tid);

    const int kv0 = t * 64;

    // scores: S = Q * K^T
    f32x4 sc[4] = {};
#pragma unroll
    for (int kk = 0; kk < 2; ++kk) {
#pragma unroll
      for (int j = 0; j < 4; ++j) {
        bf16x8 kbf = lds_read_sw(Kb[cur], j * 16 + lr, kk * 32 + lk);
        sc[j] = __builtin_amdgcn_mfma_f32_16x16x32_bf16(qf[kk], kbf, sc[j], 0, 0, 0);
      }
    }

    const bool lastt = (kv0 == q0);
    float sv[4][4];
#pragma unroll
    for (int j = 0; j < 4; ++j)
#pragma unroll
      for (int r = 0; r < 4; ++r) {
        float s = sc[j][r];
        if (lastt && (kv0 + j * 16 + lr) > (qw + rbase + r)) s = -1e30f;
        sv[j][r] = s;
      }

    // online softmax (row stats across 16-lane groups)
#pragma unroll
    for (int r = 0; r < 4; ++r) {
      float tm = fmaxf(fmaxf(sv[0][r], sv[1][r]), fmaxf(sv[2][r], sv[3][r]));
      tm = fmaxf(tm, __shfl_xor(tm, 1));
      tm = fmaxf(tm, __shfl_xor(tm, 2));
      tm = fmaxf(tm, __shfl_xor(tm, 4));
      tm = fmaxf(tm, __shfl_xor(tm, 8));
      float mnew = fmaxf(mold[r], tm);
      float scl = __expf(mold[r] - mnew);
      float ps = 0.f;
#pragma unroll
      for (int j = 0; j < 4; ++j) {
        float p = __expf(sv[j][r] - mnew);
        sv[j][r] = p;
        ps += p;
      }
      ps += __shfl_xor(ps, 1);
      ps += __shfl_xor(ps, 2);
      ps += __shfl_xor(ps, 4);
      ps += __shfl_xor(ps, 8);
      l[r] = l[r] * scl + ps;
      mold[r] = mnew;
#pragma unroll
      for (int j = 0; j < 4; ++j) out[j][r] *= scl;
    }

    // P -> LDS (wave-private buffer; no barrier needed)
#pragma unroll
    for (int r = 0; r < 4; ++r)
#pragma unroll
      for (int j = 0; j < 4; ++j)
        Ps[w][(rbase + r) * 72 + j * 16 + lr] = f2bf(sv[j][r]);

    // PV: out += P(16x64) * V(64x64)   (V^T rows = d, swizzled)
#pragma unroll
    for (int kk = 0; kk < 2; ++kk) {
      bf16x8 pa = *(const bf16x8*)&Ps[w][lr * 72 + kk * 32 + lk];
#pragma unroll
      for (int j = 0; j < 4; ++j) {
        bf16x8 vbf = lds_read_sw(Vb[cur], j * 16 + lr, kk * 32 + lk);
        out[j] = __builtin_amdgcn_mfma_f32_16x16x32_bf16(pa, vbf, out[j], 0, 0, 0);
      }
    }
    __syncthreads();
  }

  // normalize + store (bf16)
#pragma unroll
  for (int r = 0; r < 4; ++r) {
    float rcp = 1.0f / l[r];
#pragma unroll
    for (int j = 0; j < 4; ++j) {
      size_t idx = basebs + (size_t)(qw + rbase + r) * D_ + hoff + j * 16 + lr;
      Op[idx] = f2bf(out[j][r] * rcp);
    }
  }
}

// ---------------------------- launch ---------------------------------------
extern "C" void kernel_launch(void* const* d_in, const int* in_sizes, int n_in,
                              void* d_out, int out_size, void* d_ws, size_t ws_size,
                              hipStream_t stream) {
  const float* q  = (const float*)d_in[0];
  const float* k  = (const float*)d_in[1];
  const float* v  = (const float*)d_in[2];
  // d_in[3] = causal mask (tril) -- semantics hard-coded in flash_attn
  const float* Wq = (const float*)d_in[4];
  const float* bq = (const float*)d_in[5];
  const float* Wk = (const float*)d_in[6];
  const float* bk = (const float*)d_in[7];
  const float* Wv = (const float*)d_in[8];
  const float* bv = (const float*)d_in[9];
  const float* Wo = (const float*)d_in[10];
  const float* bo = (const float*)d_in[11];

  const int MSD = B_ * S_;     // 4096 rows
  unsigned short* ws = (unsigned short*)d_ws;
  unsigned short* Xq  = ws;
  unsigned short* Xk  = Xq  + (size_t)MSD * D_;
  unsigned short* Xv  = Xk  + (size_t)MSD * D_;
  unsigned short* Wqb = Xv  + (size_t)MSD * D_;
  unsigned short* Wkb = Wqb + (size_t)D_ * D_;
  unsigned short* Wvb = Wkb + (size_t)D_ * D_;
  unsigned short* Wob = Wvb + (size_t)D_ * D_;
  unsigned short* Qp  = Wob + (size_t)D_ * D_;
  unsigned short* Kp  = Qp  + (size_t)MSD * D_;
  unsigned short* Vt  = Kp  + (size_t)MSD * D_;   // V^T per head: [b][h][dk][s]
  unsigned short* At  = Vt  + (size_t)MSD * D_;

  const int n4a = MSD * D_ / 4;
  const int n4w = D_ * D_ / 4;
  cvt_f32_bf16<<<n4a / 256, 256, 0, stream>>>(q,  Xq,  n4a);
  cvt_f32_bf16<<<n4a / 256, 256, 0, stream>>>(k,  Xk,  n4a);
  cvt_f32_bf16<<<n4a / 256, 256, 0, stream>>>(v,  Xv,  n4a);
  cvt_f32_bf16<<<n4w / 256, 256, 0, stream>>>(Wq, Wqb, n4w);
  cvt_f32_bf16<<<n4w / 256, 256, 0, stream>>>(Wk, Wkb, n4w);
  cvt_f32_bf16<<<n4w / 256, 256, 0, stream>>>(Wv, Wvb, n4w);
  cvt_f32_bf16<<<n4w / 256, 256, 0, stream>>>(Wo, Wob, n4w);

  dim3 gg(MSD / 128, D_ / 128);   // (32, 8)
  gemm_nt<0><<<gg, 256, 0, stream>>>(Xq, Wqb, bq, Qp, MSD, D_, D_, 0.125f);
  gemm_nt<0><<<gg, 256, 0, stream>>>(Xk, Wkb, bk, Kp, MSD, D_, D_, 1.0f);
  gemm_nt<2><<<gg, 256, 0, stream>>>(Xv, Wvb, bv, Vt, MSD, D_, D_, 1.0f);

  dim3 ga(S_ / 64, H_, B_);       // (32, 16, 2)
  flash_attn<<<ga, 256, 0, stream>>>(Qp, Kp, Vt, At);

  gemm_nt<1><<<gg, 256, 0, stream>>>(At, Wob, bo, d_out, MSD, D_, D_, 1.0f);
}

// Round 3
// 212.005 us; speedup vs baseline: 1.2531x; 1.1880x over previous
//
#include <hip/hip_runtime.h>
#include <hip/hip_bf16.h>
#include <cstdint>
#include <cstddef>

// ---------------------------------------------------------------------------
// MultiHeadAttention (B=2, S=2048, D=1024, H=16, DK=64), fp32 in/out,
// bf16 MFMA internal compute.
// cvt -> Q/K GEMM (Q pre-scaled by 1/8), V GEMM (writes V^T per head)
//     -> flash attention (swapped-operand MFMA, lane-local softmax)
//     -> O GEMM (fp32 out)
// ---------------------------------------------------------------------------

#define B_ 2
#define S_ 2048
#define D_ 1024
#define H_ 16
#define DK_ 64

typedef __attribute__((ext_vector_type(8))) short bf16x8;
typedef __attribute__((ext_vector_type(4))) float f32x4;
typedef __attribute__((ext_vector_type(4))) unsigned short u16x4;
typedef __attribute__((ext_vector_type(4))) float float4v;

__device__ __forceinline__ unsigned short f2bf(float f) {
  unsigned int u = __float_as_uint(f);
  u += 0x7FFFu + ((u >> 16) & 1u);   // round-to-nearest-even
  return (unsigned short)(u >> 16);
}

// ---------------------------- fp32 -> bf16 convert -------------------------
__global__ __launch_bounds__(256) void cvt_f32_bf16(const float* __restrict__ src,
                                                    unsigned short* __restrict__ dst,
                                                    int n4) {
  int i = blockIdx.x * 256 + threadIdx.x;
  if (i < n4) {
    float4v v = *(const float4v*)(src + (size_t)i * 4);
    u16x4 o;
    o[0] = f2bf(v[0]); o[1] = f2bf(v[1]); o[2] = f2bf(v[2]); o[3] = f2bf(v[3]);
    *(u16x4*)(dst + (size_t)i * 4) = o;
  }
}

// ---------------------------- bf16 NT GEMM ---------------------------------
// C[M,N] = (A[M,K] * W[N,K]^T + bias[N]) * scale
// MODE 0: bf16 row-major out.  MODE 1: fp32 row-major out.
// MODE 2: bf16 out transposed per head: Vt[b][h][dk][s]  (col=(h,dk), row=(b,s))
template <int MODE>
__global__ __launch_bounds__(256) void gemm_nt(const unsigned short* __restrict__ A,
                                               const unsigned short* __restrict__ W,
                                               const float* __restrict__ bias,
                                               void* __restrict__ Cout,
                                               int M, int N, int K, float scale) {
  __shared__ unsigned short As[128 * 64];
  __shared__ unsigned short Bs[128 * 64];
  const int tid  = threadIdx.x;
  const int lane = tid & 63;
  const int m0 = blockIdx.x * 128;
  const int n0 = blockIdx.y * 128;
  const int wr = ((tid >> 6) >> 1) * 64;
  const int wc = ((tid >> 6) & 1) * 64;
  const int lr = lane & 15;
  const int lk = (lane >> 4) * 8;
  f32x4 acc[4][4] = {};

  const int chunkrow = tid >> 3;
  const int chunkcol = (tid & 7) * 8;

  for (int k0 = 0; k0 < K; k0 += 64) {
    __syncthreads();
#pragma unroll
    for (int i = 0; i < 4; ++i) {
      int row = chunkrow + i * 32;
      const unsigned short* gA = A + (size_t)(m0 + row) * K + k0 + chunkcol;
      const unsigned short* gB = W + (size_t)(n0 + row) * K + k0 + chunkcol;
      unsigned short* lA = As + row * 64 + chunkcol;
      unsigned short* lB = Bs + row * 64 + chunkcol;
      __builtin_amdgcn_global_load_lds((const __attribute__((address_space(1))) void*)gA,
                                       (__attribute__((address_space(3))) void*)lA, 16, 0, 0);
      __builtin_amdgcn_global_load_lds((const __attribute__((address_space(1))) void*)gB,
                                       (__attribute__((address_space(3))) void*)lB, 16, 0, 0);
    }
    __syncthreads();
#pragma unroll
    for (int kk = 0; kk < 2; ++kk) {
      bf16x8 a[4], b[4];
#pragma unroll
      for (int m = 0; m < 4; ++m)
        a[m] = *(const bf16x8*)(As + (wr + m * 16 + lr) * 64 + kk * 32 + lk);
#pragma unroll
      for (int n = 0; n < 4; ++n)
        b[n] = *(const bf16x8*)(Bs + (wc + n * 16 + lr) * 64 + kk * 32 + lk);
#pragma unroll
      for (int m = 0; m < 4; ++m)
#pragma unroll
        for (int n = 0; n < 4; ++n)
          acc[m][n] = __builtin_amdgcn_mfma_f32_16x16x32_bf16(a[m], b[n], acc[m][n], 0, 0, 0);
    }
  }

  const int rbase = (lane >> 4) * 4;
#pragma unroll
  for (int m = 0; m < 4; ++m) {
#pragma unroll
    for (int n = 0; n < 4; ++n) {
      int col = n0 + wc + n * 16 + lr;
      float bv = bias[col];
      if (MODE == 2) {
        int row0 = m0 + wr + m * 16 + rbase;
        int bb = row0 >> 11, s = row0 & 2047;
        int h = col >> 6, dk = col & 63;
        u16x4 o;
#pragma unroll
        for (int r = 0; r < 4; ++r) o[r] = f2bf((acc[m][n][r] + bv) * scale);
        size_t idx = (((size_t)bb * H_ + h) * DK_ + dk) * S_ + s;
        *(u16x4*)((unsigned short*)Cout + idx) = o;
      } else {
#pragma unroll
        for (int r = 0; r < 4; ++r) {
          int row = m0 + wr + m * 16 + rbase + r;
          float vv = (acc[m][n][r] + bv) * scale;
          if (MODE == 1)
            ((float*)Cout)[(size_t)row * N + col] = vv;
          else
            ((unsigned short*)Cout)[(size_t)row * N + col] = f2bf(vv);
        }
      }
    }
  }
}

// ---------------------------- flash attention ------------------------------
// Grid: (S/64, H, B). 256 threads = 4 waves; wave w owns q rows [q0+16w,+16).
// Swapped-operand MFMA: QK as mfma(K,Q) -> D[kv][q]; PV as mfma(Vt,P) ->
// D[d][q]. Lane owns q = qw + (lane&15); softmax is lane-local + 2 shfl.
__device__ __forceinline__ void stage_tile(const unsigned short* __restrict__ gK,
                                           const unsigned short* __restrict__ gV,
                                           unsigned short* kb, unsigned short* vb,
                                           int tid) {
  const int w = tid >> 6, l = tid & 63;
#pragma unroll
  for (int i = 0; i < 2; ++i) {
    int X = w * 2048 + i * 1024 + l * 16;     // dest byte (linear, lane-ordered)
    int P = X ^ (((X >> 7) & 7) << 4);        // logical byte (pre-swizzled src)
    int row = P >> 7;
    int colu = (P & 127) >> 1;                // ushort col within 64-wide row
    __builtin_amdgcn_global_load_lds(
        (const __attribute__((address_space(1))) void*)(gK + (size_t)row * D_ + colu),
        (__attribute__((address_space(3))) void*)((char*)kb + X), 16, 0, 0);
    __builtin_amdgcn_global_load_lds(
        (const __attribute__((address_space(1))) void*)(gV + (size_t)row * S_ + colu),
        (__attribute__((address_space(3))) void*)((char*)vb + X), 16, 0, 0);
  }
}

__device__ __forceinline__ bf16x8 lds_read_sw(const unsigned short* base, int row, int col) {
  int P = (row * 64 + col) * 2;
  int X = P ^ ((row & 7) << 4);
  return *(const bf16x8*)((const char*)base + X);
}

__global__ __launch_bounds__(256) void flash_attn(const unsigned short* __restrict__ Qp,
                                                  const unsigned short* __restrict__ Kp,
                                                  const unsigned short* __restrict__ Vtp,
                                                  unsigned short* __restrict__ Op) {
  __shared__ unsigned short Kb[2][4096];
  __shared__ unsigned short Vb[2][4096];
  __shared__ unsigned short Ps[4][16 * 72];

  const int tid  = threadIdx.x;
  const int lane = tid & 63;
  const int w = tid >> 6;
  const int bx = blockIdx.x;
  const int qt = (bx & 1) ? (31 - (bx >> 1)) : (bx >> 1);  // causal load pairing
  const int q0 = qt * 64;
  const int h  = blockIdx.y;
  const int b  = blockIdx.z;
  const int qw = q0 + w * 16;
  const int lr = lane & 15;
  const int hi = lane >> 4;
  const int lk = hi * 8;
  const size_t basebs = (size_t)b * S_ * D_;
  const int hoff = h * DK_;

  // Q fragment = B-operand of swapped QK: Q[q=qw+lr][d = lk + 32kk .. +8]
  bf16x8 qf[2];
  {
    const unsigned short* qrow = Qp + basebs + (size_t)(qw + lr) * D_ + hoff;
    qf[0] = *(const bf16x8*)(qrow + lk);
    qf[1] = *(const bf16x8*)(qrow + 32 + lk);
  }

  float m_r = -1e30f;   // running max for q = qw + lr (lane-local)
  float l_r = 0.f;      // running denom
  f32x4 out[4] = {};    // out[j][r] = O[d = j*16 + hi*4 + r][q = lr]

  const unsigned short* gK0 = Kp + basebs + hoff;
  const unsigned short* gV0 = Vtp + ((size_t)b * H_ + h) * DK_ * S_;

  const int ntiles = q0 / 64 + 1;
  stage_tile(gK0, gV0, Kb[0], Vb[0], tid);
  __syncthreads();

  for (int t = 0; t < ntiles; ++t) {
    const int cur = t & 1;
    if (t + 1 < ntiles)
      stage_tile(gK0 + (size_t)(t + 1) * 64 * D_, gV0 + (t + 1) * 64,
                 Kb[cur ^ 1], Vb[cur ^ 1], tid);

    const bool lastt = (t == ntiles - 1);

    // QK^T swapped: sc[j] = D[kv = j*16 + hi*4 + r][q = lr]
    f32x4 sc[4] = {};
#pragma unroll
    for (int kk = 0; kk < 2; ++kk) {
#pragma unroll
      for (int j = 0; j < 4; ++j) {
        if (!lastt || j <= w) {  // wave-uniform skip above the diagonal
          bf16x8 kf = lds_read_sw(Kb[cur], j * 16 + lr, kk * 32 + lk);
          sc[j] = __builtin_amdgcn_mfma_f32_16x16x32_bf16(kf, qf[kk], sc[j], 0, 0, 0);
        }
      }
    }

    if (lastt) {  // causal mask on the diagonal tile: kv > q -> -inf
#pragma unroll
      for (int j = 0; j < 4; ++j)
#pragma unroll
        for (int r = 0; r < 4; ++r)
          if (j * 16 + hi * 4 + r > w * 16 + lr) sc[j][r] = -1e30f;
    }

    // lane-local softmax over 16 values + 2 shfl across hi-groups
    float mj[4], sj[4];
#pragma unroll
    for (int j = 0; j < 4; ++j)
      mj[j] = fmaxf(fmaxf(sc[j][0], sc[j][1]), fmaxf(sc[j][2], sc[j][3]));
    float pm = fmaxf(fmaxf(mj[0], mj[1]), fmaxf(mj[2], mj[3]));
    pm = fmaxf(pm, __shfl_xor(pm, 16));
    pm = fmaxf(pm, __shfl_xor(pm, 32));
    float mnew = fmaxf(m_r, pm);
    float scl = __expf(m_r - mnew);

    float p[4][4];
#pragma unroll
    for (int j = 0; j < 4; ++j) {
#pragma unroll
      for (int r = 0; r < 4; ++r) p[j][r] = __expf(sc[j][r] - mnew);
      sj[j] = (p[j][0] + p[j][1]) + (p[j][2] + p[j][3]);
    }
    float ps = (sj[0] + sj[1]) + (sj[2] + sj[3]);
    ps += __shfl_xor(ps, 16);
    ps += __shfl_xor(ps, 32);
    l_r = l_r * scl + ps;
    m_r = mnew;
#pragma unroll
    for (int j = 0; j < 4; ++j)
#pragma unroll
      for (int r = 0; r < 4; ++r) out[j][r] *= scl;

    // pack P -> wave-private LDS: Ps[q = lr][kv = j*16 + hi*4 + r]
#pragma unroll
    for (int j = 0; j < 4; ++j) {
      u16x4 o;
#pragma unroll
      for (int r = 0; r < 4; ++r) o[r] = f2bf(p[j][r]);
      *(u16x4*)&Ps[w][lr * 72 + j * 16 + hi * 4] = o;
    }

    // PV swapped: out[j] += mfma(Vt_j, P)  -> D[d][q]
#pragma unroll
    for (int kk = 0; kk < 2; ++kk) {
      bf16x8 pf = *(const bf16x8*)&Ps[w][lr * 72 + kk * 32 + lk];
#pragma unroll
      for (int j = 0; j < 4; ++j) {
        bf16x8 vf = lds_read_sw(Vb[cur], j * 16 + lr, kk * 32 + lk);
        out[j] = __builtin_amdgcn_mfma_f32_16x16x32_bf16(vf, pf, out[j], 0, 0, 0);
      }
    }
    __syncthreads();
  }

  // normalize + store: O[q = qw+lr][d = j*16 + hi*4 + r] as u16x4
  float rcp = 1.0f / l_r;
#pragma unroll
  for (int j = 0; j < 4; ++j) {
    u16x4 o;
#pragma unroll
    for (int r = 0; r < 4; ++r) o[r] = f2bf(out[j][r] * rcp);
    size_t idx = basebs + (size_t)(qw + lr) * D_ + hoff + j * 16 + hi * 4;
    *(u16x4*)(Op + idx) = o;
  }
}

// ---------------------------- launch ---------------------------------------
extern "C" void kernel_launch(void* const* d_in, const int* in_sizes, int n_in,
                              void* d_out, int out_size, void* d_ws, size_t ws_size,
                              hipStream_t stream) {
  const float* q  = (const float*)d_in[0];
  const float* k  = (const float*)d_in[1];
  const float* v  = (const float*)d_in[2];
  // d_in[3] = causal mask (tril) -- semantics hard-coded in flash_attn
  const float* Wq = (const float*)d_in[4];
  const float* bq = (const float*)d_in[5];
  const float* Wk = (const float*)d_in[6];
  const float* bk = (const float*)d_in[7];
  const float* Wv = (const float*)d_in[8];
  const float* bv = (const float*)d_in[9];
  const float* Wo = (const float*)d_in[10];
  const float* bo = (const float*)d_in[11];

  const int MSD = B_ * S_;     // 4096 rows
  unsigned short* ws = (unsigned short*)d_ws;
  unsigned short* Xq  = ws;
  unsigned short* Xk  = Xq  + (size_t)MSD * D_;
  unsigned short* Xv  = Xk  + (size_t)MSD * D_;
  unsigned short* Wqb = Xv  + (size_t)MSD * D_;
  unsigned short* Wkb = Wqb + (size_t)D_ * D_;
  unsigned short* Wvb = Wkb + (size_t)D_ * D_;
  unsigned short* Wob = Wvb + (size_t)D_ * D_;
  unsigned short* Qp  = Wob + (size_t)D_ * D_;
  unsigned short* Kp  = Qp  + (size_t)MSD * D_;
  unsigned short* Vt  = Kp  + (size_t)MSD * D_;   // V^T per head: [b][h][dk][s]
  unsigned short* At  = Vt  + (size_t)MSD * D_;

  const int n4a = MSD * D_ / 4;
  const int n4w = D_ * D_ / 4;
  cvt_f32_bf16<<<n4a / 256, 256, 0, stream>>>(q,  Xq,  n4a);
  cvt_f32_bf16<<<n4a / 256, 256, 0, stream>>>(k,  Xk,  n4a);
  cvt_f32_bf16<<<n4a / 256, 256, 0, stream>>>(v,  Xv,  n4a);
  cvt_f32_bf16<<<n4w / 256, 256, 0, stream>>>(Wq, Wqb, n4w);
  cvt_f32_bf16<<<n4w / 256, 256, 0, stream>>>(Wk, Wkb, n4w);
  cvt_f32_bf16<<<n4w / 256, 256, 0, stream>>>(Wv, Wvb, n4w);
  cvt_f32_bf16<<<n4w / 256, 256, 0, stream>>>(Wo, Wob, n4w);

  dim3 gg(MSD / 128, D_ / 128);   // (32, 8)
  gemm_nt<0><<<gg, 256, 0, stream>>>(Xq, Wqb, bq, Qp, MSD, D_, D_, 0.125f);
  gemm_nt<0><<<gg, 256, 0, stream>>>(Xk, Wkb, bk, Kp, MSD, D_, D_, 1.0f);
  gemm_nt<2><<<gg, 256, 0, stream>>>(Xv, Wvb, bv, Vt, MSD, D_, D_, 1.0f);

  dim3 ga(S_ / 64, H_, B_);       // (32, 16, 2)
  flash_attn<<<ga, 256, 0, stream>>>(Qp, Kp, Vt, At);

  gemm_nt<1><<<gg, 256, 0, stream>>>(At, Wob, bo, d_out, MSD, D_, D_, 1.0f);
}

// Round 5
// 184.647 us; speedup vs baseline: 1.4388x; 1.1482x over previous
//
#include <hip/hip_runtime.h>
#include <hip/hip_bf16.h>
#include <cstdint>
#include <cstddef>

// ---------------------------------------------------------------------------
// MultiHeadAttention (B=2, S=2048, D=1024, H=16, DK=64), fp32 in/out,
// bf16 MFMA internal compute.
// cvt(2 fused) -> QKV GEMM (one dispatch, grid.z; Q pre-scaled log2e/8;
// V written transposed per head) -> flash attention (swapped MFMA, LDS P
// relayout, defer-max, exp2 softmax, setprio) -> O GEMM 64x128 (fp32 out)
// ---------------------------------------------------------------------------

#define B_ 2
#define S_ 2048
#define D_ 1024
#define H_ 16
#define DK_ 64
#define QSCALE 0.1803368801111244f   /* (1/8)*log2(e): softmax in exp2 domain */

typedef __attribute__((ext_vector_type(8))) short bf16x8;
typedef __attribute__((ext_vector_type(4))) float f32x4;
typedef __attribute__((ext_vector_type(4))) unsigned short u16x4;
typedef __attribute__((ext_vector_type(4))) float float4v;
typedef __attribute__((ext_vector_type(2))) unsigned int u32x2;

__device__ __forceinline__ unsigned short f2bf(float f) {
  unsigned int u = __float_as_uint(f);
  u += 0x7FFFu + ((u >> 16) & 1u);
  return (unsigned short)(u >> 16);
}
__device__ __forceinline__ unsigned int cvt_pk_bf16(float lo, float hi) {
  unsigned int r;
  asm("v_cvt_pk_bf16_f32 %0, %1, %2" : "=v"(r) : "v"(lo), "v"(hi));
  return r;
}

// ---------------------------- fp32 -> bf16 converts ------------------------
__global__ __launch_bounds__(256) void cvt3(const float* __restrict__ s0,
                                            const float* __restrict__ s1,
                                            const float* __restrict__ s2,
                                            unsigned short* __restrict__ d0,
                                            unsigned short* __restrict__ d1,
                                            unsigned short* __restrict__ d2) {
  const float* src = blockIdx.y == 0 ? s0 : blockIdx.y == 1 ? s1 : s2;
  unsigned short* dst = blockIdx.y == 0 ? d0 : blockIdx.y == 1 ? d1 : d2;
  int i = blockIdx.x * 256 + threadIdx.x;
  float4v v = *(const float4v*)(src + (size_t)i * 4);
  u16x4 o;
  o[0] = f2bf(v[0]); o[1] = f2bf(v[1]); o[2] = f2bf(v[2]); o[3] = f2bf(v[3]);
  *(u16x4*)(dst + (size_t)i * 4) = o;
}

__global__ __launch_bounds__(256) void cvt4(const float* __restrict__ s0,
                                            const float* __restrict__ s1,
                                            const float* __restrict__ s2,
                                            const float* __restrict__ s3,
                                            unsigned short* __restrict__ d0,
                                            unsigned short* __restrict__ d1,
                                            unsigned short* __restrict__ d2,
                                            unsigned short* __restrict__ d3) {
  int z = blockIdx.y;
  const float* src = z == 0 ? s0 : z == 1 ? s1 : z == 2 ? s2 : s3;
  unsigned short* dst = z == 0 ? d0 : z == 1 ? d1 : z == 2 ? d2 : d3;
  int i = blockIdx.x * 256 + threadIdx.x;
  float4v v = *(const float4v*)(src + (size_t)i * 4);
  u16x4 o;
  o[0] = f2bf(v[0]); o[1] = f2bf(v[1]); o[2] = f2bf(v[2]); o[3] = f2bf(v[3]);
  *(u16x4*)(dst + (size_t)i * 4) = o;
}

// ---------------------------- fused QKV GEMM -------------------------------
// z=0: Q = (Xq Wq^T + bq) * QSCALE  (bf16 row-major)
// z=1: K =  Xk Wk^T + bk            (bf16 row-major)
// z=2: V =  Xv Wv^T + bv            (bf16, transposed per head [b][h][dk][s])
__global__ __launch_bounds__(256) void gemm_qkv(
    const unsigned short* __restrict__ Xq, const unsigned short* __restrict__ Xk,
    const unsigned short* __restrict__ Xv, const unsigned short* __restrict__ Wq,
    const unsigned short* __restrict__ Wk, const unsigned short* __restrict__ Wv,
    const float* __restrict__ bq, const float* __restrict__ bk,
    const float* __restrict__ bv, unsigned short* __restrict__ Qp,
    unsigned short* __restrict__ Kp, unsigned short* __restrict__ Vt) {
  const int z = blockIdx.z;
  const unsigned short* A = z == 0 ? Xq : z == 1 ? Xk : Xv;
  const unsigned short* W = z == 0 ? Wq : z == 1 ? Wk : Wv;
  const float* bias = z == 0 ? bq : z == 1 ? bk : bv;
  const int K = D_, N = D_;

  __shared__ __align__(16) unsigned short As[128 * 64];
  __shared__ __align__(16) unsigned short Bs[128 * 64];
  const int tid  = threadIdx.x;
  const int lane = tid & 63;
  const int m0 = blockIdx.x * 128;
  const int n0 = blockIdx.y * 128;
  const int wr = ((tid >> 6) >> 1) * 64;
  const int wc = ((tid >> 6) & 1) * 64;
  const int lr = lane & 15;
  const int lk = (lane >> 4) * 8;
  f32x4 acc[4][4] = {};

  const int chunkrow = tid >> 3;
  const int chunkcol = (tid & 7) * 8;

  for (int k0 = 0; k0 < K; k0 += 64) {
    __syncthreads();
#pragma unroll
    for (int i = 0; i < 4; ++i) {
      int row = chunkrow + i * 32;
      const unsigned short* gA = A + (size_t)(m0 + row) * K + k0 + chunkcol;
      const unsigned short* gB = W + (size_t)(n0 + row) * K + k0 + chunkcol;
      __builtin_amdgcn_global_load_lds((const __attribute__((address_space(1))) void*)gA,
          (__attribute__((address_space(3))) void*)(As + row * 64 + chunkcol), 16, 0, 0);
      __builtin_amdgcn_global_load_lds((const __attribute__((address_space(1))) void*)gB,
          (__attribute__((address_space(3))) void*)(Bs + row * 64 + chunkcol), 16, 0, 0);
    }
    __syncthreads();
#pragma unroll
    for (int kk = 0; kk < 2; ++kk) {
      bf16x8 a[4], b[4];
#pragma unroll
      for (int m = 0; m < 4; ++m)
        a[m] = *(const bf16x8*)(As + (wr + m * 16 + lr) * 64 + kk * 32 + lk);
#pragma unroll
      for (int n = 0; n < 4; ++n)
        b[n] = *(const bf16x8*)(Bs + (wc + n * 16 + lr) * 64 + kk * 32 + lk);
#pragma unroll
      for (int m = 0; m < 4; ++m)
#pragma unroll
        for (int n = 0; n < 4; ++n)
          acc[m][n] = __builtin_amdgcn_mfma_f32_16x16x32_bf16(a[m], b[n], acc[m][n], 0, 0, 0);
    }
  }

  const int rbase = (lane >> 4) * 4;
  if (z == 2) {
#pragma unroll
    for (int m = 0; m < 4; ++m)
#pragma unroll
      for (int n = 0; n < 4; ++n) {
        int col = n0 + wc + n * 16 + lr;
        float bvv = bias[col];
        int row0 = m0 + wr + m * 16 + rbase;
        int bb = row0 >> 11, s = row0 & 2047;
        int h = col >> 6, dk = col & 63;
        u16x4 o;
#pragma unroll
        for (int r = 0; r < 4; ++r) o[r] = f2bf(acc[m][n][r] + bvv);
        size_t idx = (((size_t)bb * H_ + h) * DK_ + dk) * S_ + s;
        *(u16x4*)(Vt + idx) = o;
      }
  } else {
    unsigned short* Cout = z == 0 ? Qp : Kp;
    const float scale = z == 0 ? QSCALE : 1.0f;
#pragma unroll
    for (int m = 0; m < 4; ++m)
#pragma unroll
      for (int n = 0; n < 4; ++n) {
        int col = n0 + wc + n * 16 + lr;
        float bvv = bias[col];
#pragma unroll
        for (int r = 0; r < 4; ++r) {
          int row = m0 + wr + m * 16 + rbase + r;
          Cout[(size_t)row * N + col] = f2bf((acc[m][n][r] + bvv) * scale);
        }
      }
  }
}

// ---------------------------- O GEMM (64x128 tile) -------------------------
__global__ __launch_bounds__(256) void gemm_o(const unsigned short* __restrict__ A,
                                              const unsigned short* __restrict__ W,
                                              const float* __restrict__ bias,
                                              float* __restrict__ C,
                                              int M, int N, int K) {
  __shared__ __align__(16) unsigned short As[64 * 64];
  __shared__ __align__(16) unsigned short Bs[128 * 64];
  const int tid  = threadIdx.x;
  const int lane = tid & 63;
  const int m0 = blockIdx.x * 64;
  const int n0 = blockIdx.y * 128;
  const int wr = ((tid >> 6) >> 1) * 32;
  const int wc = ((tid >> 6) & 1) * 64;
  const int lr = lane & 15;
  const int lk = (lane >> 4) * 8;
  f32x4 acc[2][4] = {};

  const int chunkrow = tid >> 3;
  const int chunkcol = (tid & 7) * 8;

  for (int k0 = 0; k0 < K; k0 += 64) {
    __syncthreads();
#pragma unroll
    for (int i = 0; i < 2; ++i) {
      int row = chunkrow + i * 32;
      const unsigned short* gA = A + (size_t)(m0 + row) * K + k0 + chunkcol;
      __builtin_amdgcn_global_load_lds((const __attribute__((address_space(1))) void*)gA,
          (__attribute__((address_space(3))) void*)(As + row * 64 + chunkcol), 16, 0, 0);
    }
#pragma unroll
    for (int i = 0; i < 4; ++i) {
      int row = chunkrow + i * 32;
      const unsigned short* gB = W + (size_t)(n0 + row) * K + k0 + chunkcol;
      __builtin_amdgcn_global_load_lds((const __attribute__((address_space(1))) void*)gB,
          (__attribute__((address_space(3))) void*)(Bs + row * 64 + chunkcol), 16, 0, 0);
    }
    __syncthreads();
#pragma unroll
    for (int kk = 0; kk < 2; ++kk) {
      bf16x8 a[2], b[4];
#pragma unroll
      for (int m = 0; m < 2; ++m)
        a[m] = *(const bf16x8*)(As + (wr + m * 16 + lr) * 64 + kk * 32 + lk);
#pragma unroll
      for (int n = 0; n < 4; ++n)
        b[n] = *(const bf16x8*)(Bs + (wc + n * 16 + lr) * 64 + kk * 32 + lk);
#pragma unroll
      for (int m = 0; m < 2; ++m)
#pragma unroll
        for (int n = 0; n < 4; ++n)
          acc[m][n] = __builtin_amdgcn_mfma_f32_16x16x32_bf16(a[m], b[n], acc[m][n], 0, 0, 0);
    }
  }

  const int rbase = (lane >> 4) * 4;
#pragma unroll
  for (int m = 0; m < 2; ++m)
#pragma unroll
    for (int n = 0; n < 4; ++n) {
      int col = n0 + wc + n * 16 + lr;
      float bvv = bias[col];
#pragma unroll
      for (int r = 0; r < 4; ++r) {
        int row = m0 + wr + m * 16 + rbase + r;
        C[(size_t)row * N + col] = acc[m][n][r] + bvv;
      }
    }
}

// ---------------------------- flash attention ------------------------------
// Grid: (S/64, H, B). 4 waves; wave w owns q rows [q0+16w,+16).
// QK as mfma(K,Q) -> D[kv][q]; PV as mfma(Vt,P) -> D[d][q].
// P relayout via wave-private LDS Ps (proven R3 path), packed with cvt_pk.
__device__ __forceinline__ void stage_tile(const unsigned short* __restrict__ gK,
                                           const unsigned short* __restrict__ gV,
                                           unsigned short* kb, unsigned short* vb,
                                           int tid) {
  const int w = tid >> 6, l = tid & 63;
#pragma unroll
  for (int i = 0; i < 2; ++i) {
    int X = w * 2048 + i * 1024 + l * 16;     // dest byte (linear, lane-ordered)
    int P = X ^ (((X >> 7) & 7) << 4);        // logical byte (pre-swizzled src)
    int row = P >> 7;
    int colu = (P & 127) >> 1;
    __builtin_amdgcn_global_load_lds(
        (const __attribute__((address_space(1))) void*)(gK + (size_t)row * D_ + colu),
        (__attribute__((address_space(3))) void*)((char*)kb + X), 16, 0, 0);
    __builtin_amdgcn_global_load_lds(
        (const __attribute__((address_space(1))) void*)(gV + (size_t)row * S_ + colu),
        (__attribute__((address_space(3))) void*)((char*)vb + X), 16, 0, 0);
  }
}

__device__ __forceinline__ bf16x8 lds_read_sw(const unsigned short* base, int row, int col) {
  int P = (row * 64 + col) * 2;
  int X = P ^ ((row & 7) << 4);
  return *(const bf16x8*)((const char*)base + X);
}

__global__ __launch_bounds__(256) void flash_attn(const unsigned short* __restrict__ Qp,
                                                  const unsigned short* __restrict__ Kp,
                                                  const unsigned short* __restrict__ Vtp,
                                                  unsigned short* __restrict__ Op) {
  __shared__ __align__(16) unsigned short Kb[2][4096];
  __shared__ __align__(16) unsigned short Vb[2][4096];
  __shared__ __align__(16) unsigned short Ps[4][16 * 72];

  const int tid  = threadIdx.x;
  const int lane = tid & 63;
  const int w = tid >> 6;
  const int bx = blockIdx.x;
  const int qt = (bx & 1) ? (31 - (bx >> 1)) : (bx >> 1);
  const int q0 = qt * 64;
  const int h  = blockIdx.y;
  const int b  = blockIdx.z;
  const int qw = q0 + w * 16;
  const int lr = lane & 15;
  const int hi = lane >> 4;
  const int lk = hi * 8;
  const size_t basebs = (size_t)b * S_ * D_;
  const int hoff = h * DK_;

  bf16x8 qf[2];
  {
    const unsigned short* qrow = Qp + basebs + (size_t)(qw + lr) * D_ + hoff;
    qf[0] = *(const bf16x8*)(qrow + lk);
    qf[1] = *(const bf16x8*)(qrow + 32 + lk);
  }

  float m_r = -1e30f;   // running max (log2 domain), q = qw + lr
  float l_r = 0.f;
  f32x4 out[4] = {};    // out[j][r] = O[d = j*16 + hi*4 + r][q = lr]

  const unsigned short* gK0 = Kp + basebs + hoff;
  const unsigned short* gV0 = Vtp + ((size_t)b * H_ + h) * DK_ * S_;

  const int ntiles = q0 / 64 + 1;
  stage_tile(gK0, gV0, Kb[0], Vb[0], tid);
  __syncthreads();

  for (int t = 0; t < ntiles; ++t) {
    const int cur = t & 1;
    if (t + 1 < ntiles)
      stage_tile(gK0 + (size_t)(t + 1) * 64 * D_, gV0 + (t + 1) * 64,
                 Kb[cur ^ 1], Vb[cur ^ 1], tid);

    const bool lastt = (t == ntiles - 1);

    // QK^T swapped: sc[j] = D[kv = j*16 + hi*4 + r][q = lr]
    f32x4 sc[4] = {};
    __builtin_amdgcn_s_setprio(1);
#pragma unroll
    for (int kk = 0; kk < 2; ++kk) {
#pragma unroll
      for (int j = 0; j < 4; ++j) {
        if (!lastt || j <= w) {
          bf16x8 kf = lds_read_sw(Kb[cur], j * 16 + lr, kk * 32 + lk);
          sc[j] = __builtin_amdgcn_mfma_f32_16x16x32_bf16(kf, qf[kk], sc[j], 0, 0, 0);
        }
      }
    }
    __builtin_amdgcn_s_setprio(0);

    if (lastt) {
#pragma unroll
      for (int j = 0; j < 4; ++j)
#pragma unroll
        for (int r = 0; r < 4; ++r)
          if (j * 16 + hi * 4 + r > w * 16 + lr) sc[j][r] = -1e30f;
    }

    // row max (lane-local 16 + 2 shfl)
    float mj0 = fmaxf(fmaxf(sc[0][0], sc[0][1]), fmaxf(sc[0][2], sc[0][3]));
    float mj1 = fmaxf(fmaxf(sc[1][0], sc[1][1]), fmaxf(sc[1][2], sc[1][3]));
    float mj2 = fmaxf(fmaxf(sc[2][0], sc[2][1]), fmaxf(sc[2][2], sc[2][3]));
    float mj3 = fmaxf(fmaxf(sc[3][0], sc[3][1]), fmaxf(sc[3][2], sc[3][3]));
    float pm = fmaxf(fmaxf(mj0, mj1), fmaxf(mj2, mj3));
    pm = fmaxf(pm, __shfl_xor(pm, 16));
    pm = fmaxf(pm, __shfl_xor(pm, 32));

    // defer-max: rescale only when the running max grew by > 8 (2^8 headroom)
    if (!__all(pm - m_r <= 8.0f)) {
      float mnew = fmaxf(m_r, pm);
      float scl = __builtin_exp2f(m_r - mnew);
      l_r *= scl;
#pragma unroll
      for (int j = 0; j < 4; ++j)
#pragma unroll
        for (int r = 0; r < 4; ++r) out[j][r] *= scl;
      m_r = mnew;
    }

    // P = exp2(sc - m_r); pack via cvt_pk into wave-private LDS
    float l_add = 0.f;
#pragma unroll
    for (int j = 0; j < 4; ++j) {
      float p0 = __builtin_exp2f(sc[j][0] - m_r);
      float p1 = __builtin_exp2f(sc[j][1] - m_r);
      float p2 = __builtin_exp2f(sc[j][2] - m_r);
      float p3 = __builtin_exp2f(sc[j][3] - m_r);
      l_add += (p0 + p1) + (p2 + p3);
      u32x2 o = {cvt_pk_bf16(p0, p1), cvt_pk_bf16(p2, p3)};
      // Ps[q = lr][kv = j*16 + hi*4 + {0..3}]
      *(u32x2*)&Ps[w][lr * 72 + j * 16 + hi * 4] = o;
    }
    l_add += __shfl_xor(l_add, 16);
    l_add += __shfl_xor(l_add, 32);
    l_r += l_add;

    // PV swapped: out[j] += mfma(Vt_j, P) -> D[d][q]
#pragma unroll
    for (int kk = 0; kk < 2; ++kk) {
      bf16x8 pf = *(const bf16x8*)&Ps[w][lr * 72 + kk * 32 + lk];
      __builtin_amdgcn_s_setprio(1);
#pragma unroll
      for (int j = 0; j < 4; ++j) {
        bf16x8 vf = lds_read_sw(Vb[cur], j * 16 + lr, kk * 32 + lk);
        out[j] = __builtin_amdgcn_mfma_f32_16x16x32_bf16(vf, pf, out[j], 0, 0, 0);
      }
      __builtin_amdgcn_s_setprio(0);
    }
    __syncthreads();
  }

  // normalize + store: O[q = qw+lr][d = j*16 + hi*4 + r]
  float rcp = 1.0f / l_r;
#pragma unroll
  for (int j = 0; j < 4; ++j) {
    u32x2 o = {cvt_pk_bf16(out[j][0] * rcp, out[j][1] * rcp),
               cvt_pk_bf16(out[j][2] * rcp, out[j][3] * rcp)};
    size_t idx = basebs + (size_t)(qw + lr) * D_ + hoff + j * 16 + hi * 4;
    *(u32x2*)(Op + idx) = o;
  }
}

// ---------------------------- launch ---------------------------------------
extern "C" void kernel_launch(void* const* d_in, const int* in_sizes, int n_in,
                              void* d_out, int out_size, void* d_ws, size_t ws_size,
                              hipStream_t stream) {
  const float* q  = (const float*)d_in[0];
  const float* k  = (const float*)d_in[1];
  const float* v  = (const float*)d_in[2];
  // d_in[3] = causal mask (tril) -- semantics hard-coded in flash_attn
  const float* Wq = (const float*)d_in[4];
  const float* bq = (const float*)d_in[5];
  const float* Wk = (const float*)d_in[6];
  const float* bk = (const float*)d_in[7];
  const float* Wv = (const float*)d_in[8];
  const float* bv = (const float*)d_in[9];
  const float* Wo = (const float*)d_in[10];
  const float* bo = (const float*)d_in[11];

  const int MSD = B_ * S_;     // 4096 rows
  unsigned short* ws = (unsigned short*)d_ws;
  unsigned short* Xq  = ws;
  unsigned short* Xk  = Xq  + (size_t)MSD * D_;
  unsigned short* Xv  = Xk  + (size_t)MSD * D_;
  unsigned short* Wqb = Xv  + (size_t)MSD * D_;
  unsigned short* Wkb = Wqb + (size_t)D_ * D_;
  unsigned short* Wvb = Wkb + (size_t)D_ * D_;
  unsigned short* Wob = Wvb + (size_t)D_ * D_;
  unsigned short* Qp  = Wob + (size_t)D_ * D_;
  unsigned short* Kp  = Qp  + (size_t)MSD * D_;
  unsigned short* Vt  = Kp  + (size_t)MSD * D_;   // V^T per head: [b][h][dk][s]
  unsigned short* At  = Vt  + (size_t)MSD * D_;

  const int n4a = MSD * D_ / 4;   // 1048576
  const int n4w = D_ * D_ / 4;    // 262144
  dim3 g3(n4a / 256, 3);
  cvt3<<<g3, 256, 0, stream>>>(q, k, v, Xq, Xk, Xv);
  dim3 g4(n4w / 256, 4);
  cvt4<<<g4, 256, 0, stream>>>(Wq, Wk, Wv, Wo, Wqb, Wkb, Wvb, Wob);

  dim3 gqkv(MSD / 128, D_ / 128, 3);   // (32, 8, 3) = 768 blocks
  gemm_qkv<<<gqkv, 256, 0, stream>>>(Xq, Xk, Xv, Wqb, Wkb, Wvb,
                                     bq, bk, bv, Qp, Kp, Vt);

  dim3 ga(S_ / 64, H_, B_);            // (32, 16, 2)
  flash_attn<<<ga, 256, 0, stream>>>(Qp, Kp, Vt, At);

  dim3 go(MSD / 64, D_ / 128);         // (64, 8) = 512 blocks
  gemm_o<<<go, 256, 0, stream>>>(At, Wob, bo, (float*)d_out, MSD, D_, D_);
}

// Round 6
// 168.274 us; speedup vs baseline: 1.5788x; 1.0973x over previous
//
#include <hip/hip_runtime.h>
#include <hip/hip_bf16.h>
#include <cstdint>
#include <cstddef>

// ---------------------------------------------------------------------------
// MultiHeadAttention (B=2, S=2048, D=1024, H=16, DK=64), fp32 in/out,
// bf16 MFMA internal compute.
// cvt(2 fused) -> QKV GEMM (one dispatch, grid.z; Q pre-scaled log2e/8;
// V written transposed per head) -> flash attention (32x32x16 MFMA, 32 q-rows
// per wave, QBLK=128, lane-local softmax w/ 1 shfl, defer-max, LDS P path)
// -> O GEMM 64x128 (fp32 out)
// ---------------------------------------------------------------------------

#define B_ 2
#define S_ 2048
#define D_ 1024
#define H_ 16
#define DK_ 64
#define QSCALE 0.1803368801111244f   /* (1/8)*log2(e): softmax in exp2 domain */

typedef __attribute__((ext_vector_type(8))) short bf16x8;
typedef __attribute__((ext_vector_type(4))) float f32x4;
typedef __attribute__((ext_vector_type(16))) float f32x16;
typedef __attribute__((ext_vector_type(4))) unsigned short u16x4;
typedef __attribute__((ext_vector_type(4))) float float4v;
typedef __attribute__((ext_vector_type(2))) unsigned int u32x2;

__device__ __forceinline__ unsigned short f2bf(float f) {
  unsigned int u = __float_as_uint(f);
  u += 0x7FFFu + ((u >> 16) & 1u);
  return (unsigned short)(u >> 16);
}
__device__ __forceinline__ unsigned int cvt_pk_bf16(float lo, float hi) {
  unsigned int r;
  asm("v_cvt_pk_bf16_f32 %0, %1, %2" : "=v"(r) : "v"(lo), "v"(hi));
  return r;
}

// ---------------------------- fp32 -> bf16 converts ------------------------
__global__ __launch_bounds__(256) void cvt3(const float* __restrict__ s0,
                                            const float* __restrict__ s1,
                                            const float* __restrict__ s2,
                                            unsigned short* __restrict__ d0,
                                            unsigned short* __restrict__ d1,
                                            unsigned short* __restrict__ d2) {
  const float* src = blockIdx.y == 0 ? s0 : blockIdx.y == 1 ? s1 : s2;
  unsigned short* dst = blockIdx.y == 0 ? d0 : blockIdx.y == 1 ? d1 : d2;
  int i = blockIdx.x * 256 + threadIdx.x;
  float4v v = *(const float4v*)(src + (size_t)i * 4);
  u16x4 o;
  o[0] = f2bf(v[0]); o[1] = f2bf(v[1]); o[2] = f2bf(v[2]); o[3] = f2bf(v[3]);
  *(u16x4*)(dst + (size_t)i * 4) = o;
}

__global__ __launch_bounds__(256) void cvt4(const float* __restrict__ s0,
                                            const float* __restrict__ s1,
                                            const float* __restrict__ s2,
                                            const float* __restrict__ s3,
                                            unsigned short* __restrict__ d0,
                                            unsigned short* __restrict__ d1,
                                            unsigned short* __restrict__ d2,
                                            unsigned short* __restrict__ d3) {
  int z = blockIdx.y;
  const float* src = z == 0 ? s0 : z == 1 ? s1 : z == 2 ? s2 : s3;
  unsigned short* dst = z == 0 ? d0 : z == 1 ? d1 : z == 2 ? d2 : d3;
  int i = blockIdx.x * 256 + threadIdx.x;
  float4v v = *(const float4v*)(src + (size_t)i * 4);
  u16x4 o;
  o[0] = f2bf(v[0]); o[1] = f2bf(v[1]); o[2] = f2bf(v[2]); o[3] = f2bf(v[3]);
  *(u16x4*)(dst + (size_t)i * 4) = o;
}

// ---------------------------- fused QKV GEMM -------------------------------
__global__ __launch_bounds__(256) void gemm_qkv(
    const unsigned short* __restrict__ Xq, const unsigned short* __restrict__ Xk,
    const unsigned short* __restrict__ Xv, const unsigned short* __restrict__ Wq,
    const unsigned short* __restrict__ Wk, const unsigned short* __restrict__ Wv,
    const float* __restrict__ bq, const float* __restrict__ bk,
    const float* __restrict__ bv, unsigned short* __restrict__ Qp,
    unsigned short* __restrict__ Kp, unsigned short* __restrict__ Vt) {
  const int z = blockIdx.z;
  const unsigned short* A = z == 0 ? Xq : z == 1 ? Xk : Xv;
  const unsigned short* W = z == 0 ? Wq : z == 1 ? Wk : Wv;
  const float* bias = z == 0 ? bq : z == 1 ? bk : bv;
  const int K = D_, N = D_;

  __shared__ __align__(16) unsigned short As[128 * 64];
  __shared__ __align__(16) unsigned short Bs[128 * 64];
  const int tid  = threadIdx.x;
  const int lane = tid & 63;
  const int m0 = blockIdx.x * 128;
  const int n0 = blockIdx.y * 128;
  const int wr = ((tid >> 6) >> 1) * 64;
  const int wc = ((tid >> 6) & 1) * 64;
  const int lr = lane & 15;
  const int lk = (lane >> 4) * 8;
  f32x4 acc[4][4] = {};

  const int chunkrow = tid >> 3;
  const int chunkcol = (tid & 7) * 8;

  for (int k0 = 0; k0 < K; k0 += 64) {
    __syncthreads();
#pragma unroll
    for (int i = 0; i < 4; ++i) {
      int row = chunkrow + i * 32;
      const unsigned short* gA = A + (size_t)(m0 + row) * K + k0 + chunkcol;
      const unsigned short* gB = W + (size_t)(n0 + row) * K + k0 + chunkcol;
      __builtin_amdgcn_global_load_lds((const __attribute__((address_space(1))) void*)gA,
          (__attribute__((address_space(3))) void*)(As + row * 64 + chunkcol), 16, 0, 0);
      __builtin_amdgcn_global_load_lds((const __attribute__((address_space(1))) void*)gB,
          (__attribute__((address_space(3))) void*)(Bs + row * 64 + chunkcol), 16, 0, 0);
    }
    __syncthreads();
#pragma unroll
    for (int kk = 0; kk < 2; ++kk) {
      bf16x8 a[4], b[4];
#pragma unroll
      for (int m = 0; m < 4; ++m)
        a[m] = *(const bf16x8*)(As + (wr + m * 16 + lr) * 64 + kk * 32 + lk);
#pragma unroll
      for (int n = 0; n < 4; ++n)
        b[n] = *(const bf16x8*)(Bs + (wc + n * 16 + lr) * 64 + kk * 32 + lk);
#pragma unroll
      for (int m = 0; m < 4; ++m)
#pragma unroll
        for (int n = 0; n < 4; ++n)
          acc[m][n] = __builtin_amdgcn_mfma_f32_16x16x32_bf16(a[m], b[n], acc[m][n], 0, 0, 0);
    }
  }

  const int rbase = (lane >> 4) * 4;
  if (z == 2) {
#pragma unroll
    for (int m = 0; m < 4; ++m)
#pragma unroll
      for (int n = 0; n < 4; ++n) {
        int col = n0 + wc + n * 16 + lr;
        float bvv = bias[col];
        int row0 = m0 + wr + m * 16 + rbase;
        int bb = row0 >> 11, s = row0 & 2047;
        int h = col >> 6, dk = col & 63;
        u16x4 o;
#pragma unroll
        for (int r = 0; r < 4; ++r) o[r] = f2bf(acc[m][n][r] + bvv);
        size_t idx = (((size_t)bb * H_ + h) * DK_ + dk) * S_ + s;
        *(u16x4*)(Vt + idx) = o;
      }
  } else {
    unsigned short* Cout = z == 0 ? Qp : Kp;
    const float scale = z == 0 ? QSCALE : 1.0f;
#pragma unroll
    for (int m = 0; m < 4; ++m)
#pragma unroll
      for (int n = 0; n < 4; ++n) {
        int col = n0 + wc + n * 16 + lr;
        float bvv = bias[col];
#pragma unroll
        for (int r = 0; r < 4; ++r) {
          int row = m0 + wr + m * 16 + rbase + r;
          Cout[(size_t)row * N + col] = f2bf((acc[m][n][r] + bvv) * scale);
        }
      }
  }
}

// ---------------------------- O GEMM (64x128 tile) -------------------------
__global__ __launch_bounds__(256) void gemm_o(const unsigned short* __restrict__ A,
                                              const unsigned short* __restrict__ W,
                                              const float* __restrict__ bias,
                                              float* __restrict__ C,
                                              int M, int N, int K) {
  __shared__ __align__(16) unsigned short As[64 * 64];
  __shared__ __align__(16) unsigned short Bs[128 * 64];
  const int tid  = threadIdx.x;
  const int lane = tid & 63;
  const int m0 = blockIdx.x * 64;
  const int n0 = blockIdx.y * 128;
  const int wr = ((tid >> 6) >> 1) * 32;
  const int wc = ((tid >> 6) & 1) * 64;
  const int lr = lane & 15;
  const int lk = (lane >> 4) * 8;
  f32x4 acc[2][4] = {};

  const int chunkrow = tid >> 3;
  const int chunkcol = (tid & 7) * 8;

  for (int k0 = 0; k0 < K; k0 += 64) {
    __syncthreads();
#pragma unroll
    for (int i = 0; i < 2; ++i) {
      int row = chunkrow + i * 32;
      const unsigned short* gA = A + (size_t)(m0 + row) * K + k0 + chunkcol;
      __builtin_amdgcn_global_load_lds((const __attribute__((address_space(1))) void*)gA,
          (__attribute__((address_space(3))) void*)(As + row * 64 + chunkcol), 16, 0, 0);
    }
#pragma unroll
    for (int i = 0; i < 4; ++i) {
      int row = chunkrow + i * 32;
      const unsigned short* gB = W + (size_t)(n0 + row) * K + k0 + chunkcol;
      __builtin_amdgcn_global_load_lds((const __attribute__((address_space(1))) void*)gB,
          (__attribute__((address_space(3))) void*)(Bs + row * 64 + chunkcol), 16, 0, 0);
    }
    __syncthreads();
#pragma unroll
    for (int kk = 0; kk < 2; ++kk) {
      bf16x8 a[2], b[4];
#pragma unroll
      for (int m = 0; m < 2; ++m)
        a[m] = *(const bf16x8*)(As + (wr + m * 16 + lr) * 64 + kk * 32 + lk);
#pragma unroll
      for (int n = 0; n < 4; ++n)
        b[n] = *(const bf16x8*)(Bs + (wc + n * 16 + lr) * 64 + kk * 32 + lk);
#pragma unroll
      for (int m = 0; m < 2; ++m)
#pragma unroll
        for (int n = 0; n < 4; ++n)
          acc[m][n] = __builtin_amdgcn_mfma_f32_16x16x32_bf16(a[m], b[n], acc[m][n], 0, 0, 0);
    }
  }

  const int rbase = (lane >> 4) * 4;
#pragma unroll
  for (int m = 0; m < 2; ++m)
#pragma unroll
    for (int n = 0; n < 4; ++n) {
      int col = n0 + wc + n * 16 + lr;
      float bvv = bias[col];
#pragma unroll
      for (int r = 0; r < 4; ++r) {
        int row = m0 + wr + m * 16 + rbase + r;
        C[(size_t)row * N + col] = acc[m][n][r] + bvv;
      }
    }
}

// ---------------------------- flash attention ------------------------------
// Grid: (S/128, H, B). 4 waves; wave w owns q rows [q0+32w, +32).
// mfma_f32_32x32x16_bf16, swapped operands:
//   QK: sc = mfma(K_frag, Q_frag) -> D[kv][q], q = lane&31 (lane-local!)
//   PV: out = mfma(Vt_frag, P_frag) -> D[d][q]
// A-frag: row=lane&31, k=(lane>>5)*8+e.  B-frag: col=lane&31, same k.
// C/D: col=lane&31, row=(reg&3)+8*(reg>>2)+4*(lane>>5).
__device__ __forceinline__ void stage_tile(const unsigned short* __restrict__ gK,
                                           const unsigned short* __restrict__ gV,
                                           unsigned short* kb, unsigned short* vb,
                                           int tid) {
  const int w = tid >> 6, l = tid & 63;
#pragma unroll
  for (int i = 0; i < 2; ++i) {
    int X = w * 2048 + i * 1024 + l * 16;     // dest byte (linear, lane-ordered)
    int P = X ^ (((X >> 7) & 7) << 4);        // logical byte (pre-swizzled src)
    int row = P >> 7;
    int colu = (P & 127) >> 1;
    __builtin_amdgcn_global_load_lds(
        (const __attribute__((address_space(1))) void*)(gK + (size_t)row * D_ + colu),
        (__attribute__((address_space(3))) void*)((char*)kb + X), 16, 0, 0);
    __builtin_amdgcn_global_load_lds(
        (const __attribute__((address_space(1))) void*)(gV + (size_t)row * S_ + colu),
        (__attribute__((address_space(3))) void*)((char*)vb + X), 16, 0, 0);
  }
}

__device__ __forceinline__ bf16x8 lds_read_sw(const unsigned short* base, int row, int col) {
  int P = (row * 64 + col) * 2;
  int X = P ^ ((row & 7) << 4);
  return *(const bf16x8*)((const char*)base + X);
}

__global__ __launch_bounds__(256) void flash_attn(const unsigned short* __restrict__ Qp,
                                                  const unsigned short* __restrict__ Kp,
                                                  const unsigned short* __restrict__ Vtp,
                                                  unsigned short* __restrict__ Op) {
  __shared__ __align__(16) unsigned short Kb[2][4096];   // [kv 64][d 64] swizzled
  __shared__ __align__(16) unsigned short Vb[2][4096];   // [d 64][kv 64] swizzled
  __shared__ __align__(16) unsigned short Ps[4][32 * 68];// per-wave P [q 32][kv 64+4]

  const int tid  = threadIdx.x;
  const int lane = tid & 63;
  const int w = tid >> 6;
  const int bx = blockIdx.x;
  const int qt = (bx & 1) ? (15 - (bx >> 1)) : (bx >> 1);  // causal pairing
  const int q0 = qt * 128;
  const int h  = blockIdx.y;
  const int b  = blockIdx.z;
  const int ql = lane & 31;
  const int hi5 = lane >> 5;
  const int qbase = q0 + w * 32;
  const int qglob = qbase + ql;
  const size_t basebs = (size_t)b * S_ * D_;
  const int hoff = h * DK_;

  // Q B-frag: qf[f] = Q[qglob][hoff + f*16 + hi5*8 .. +8]
  bf16x8 qf[4];
  {
    const unsigned short* qrow = Qp + basebs + (size_t)qglob * D_ + hoff;
#pragma unroll
    for (int f = 0; f < 4; ++f)
      qf[f] = *(const bf16x8*)(qrow + f * 16 + hi5 * 8);
  }

  float m_r = -1e30f;   // running max (log2 domain) for q = qglob
  float l_r = 0.f;
  f32x16 out0 = {};     // d-tile 0: d = (reg&3)+8*(reg>>2)+4*hi5
  f32x16 out1 = {};     // d-tile 1: d = 32 + same

  const unsigned short* gK0 = Kp + basebs + hoff;
  const unsigned short* gV0 = Vtp + ((size_t)b * H_ + h) * DK_ * S_;

  const int T = q0 / 64 + 2;
  stage_tile(gK0, gV0, Kb[0], Vb[0], tid);
  __syncthreads();

  for (int t = 0; t < T; ++t) {
    const int cur = t & 1;
    if (t + 1 < T)
      stage_tile(gK0 + (size_t)(t + 1) * 64 * D_, gV0 + (t + 1) * 64,
                 Kb[cur ^ 1], Vb[cur ^ 1], tid);

    const int kv0 = t * 64;
    const bool do0 = (kv0 <= qbase);        // subtile kv [kv0, kv0+32) active
    const bool do1 = (kv0 + 32 <= qbase);   // subtile kv [kv0+32, kv0+64) active
    const bool part0 = (kv0 == qbase);      // diagonal -> per-element mask
    const bool part1 = (kv0 + 32 == qbase);

    if (do0) {
      f32x16 sc0 = {}, sc1 = {};
      __builtin_amdgcn_s_setprio(1);
#pragma unroll
      for (int f = 0; f < 4; ++f) {
        bf16x8 kf = lds_read_sw(Kb[cur], ql, f * 16 + hi5 * 8);
        sc0 = __builtin_amdgcn_mfma_f32_32x32x16_bf16(kf, qf[f], sc0, 0, 0, 0);
      }
      if (do1) {
#pragma unroll
        for (int f = 0; f < 4; ++f) {
          bf16x8 kf = lds_read_sw(Kb[cur], 32 + ql, f * 16 + hi5 * 8);
          sc1 = __builtin_amdgcn_mfma_f32_32x32x16_bf16(kf, qf[f], sc1, 0, 0, 0);
        }
      }
      __builtin_amdgcn_s_setprio(0);

      if (part0) {
#pragma unroll
        for (int g = 0; g < 16; ++g) {
          int kvg = kv0 + (g & 3) + 8 * (g >> 2) + 4 * hi5;
          if (kvg > qglob) sc0[g] = -1e30f;
        }
      }
      if (do1 && part1) {
#pragma unroll
        for (int g = 0; g < 16; ++g) {
          int kvg = kv0 + 32 + (g & 3) + 8 * (g >> 2) + 4 * hi5;
          if (kvg > qglob) sc1[g] = -1e30f;
        }
      }

      // row max: local regs + one cross-half shfl
      float pm = sc0[0];
#pragma unroll
      for (int g = 1; g < 16; ++g) pm = fmaxf(pm, sc0[g]);
      if (do1) {
#pragma unroll
        for (int g = 0; g < 16; ++g) pm = fmaxf(pm, sc1[g]);
      }
      pm = fmaxf(pm, __shfl_xor(pm, 32));

      // defer-max: rescale only when running max grew by > 8 (2^8 headroom)
      if (!__all(pm - m_r <= 8.0f)) {
        float mnew = fmaxf(m_r, pm);
        float scl = __builtin_exp2f(m_r - mnew);
        l_r *= scl;
#pragma unroll
        for (int g = 0; g < 16; ++g) { out0[g] *= scl; out1[g] *= scl; }
        m_r = mnew;
      }

      // P = exp2(sc - m_r) -> bf16 pack -> wave-private LDS Ps[q][kv]
      float l_add = 0.f;
#pragma unroll
      for (int i = 0; i < 4; ++i) {
        float p0 = __builtin_exp2f(sc0[4 * i + 0] - m_r);
        float p1 = __builtin_exp2f(sc0[4 * i + 1] - m_r);
        float p2 = __builtin_exp2f(sc0[4 * i + 2] - m_r);
        float p3 = __builtin_exp2f(sc0[4 * i + 3] - m_r);
        l_add += (p0 + p1) + (p2 + p3);
        u32x2 o = {cvt_pk_bf16(p0, p1), cvt_pk_bf16(p2, p3)};
        *(u32x2*)&Ps[w][ql * 68 + 8 * i + 4 * hi5] = o;
      }
      if (do1) {
#pragma unroll
        for (int i = 0; i < 4; ++i) {
          float p0 = __builtin_exp2f(sc1[4 * i + 0] - m_r);
          float p1 = __builtin_exp2f(sc1[4 * i + 1] - m_r);
          float p2 = __builtin_exp2f(sc1[4 * i + 2] - m_r);
          float p3 = __builtin_exp2f(sc1[4 * i + 3] - m_r);
          l_add += (p0 + p1) + (p2 + p3);
          u32x2 o = {cvt_pk_bf16(p0, p1), cvt_pk_bf16(p2, p3)};
          *(u32x2*)&Ps[w][ql * 68 + 32 + 8 * i + 4 * hi5] = o;
        }
      }
      l_add += __shfl_xor(l_add, 32);
      l_r += l_add;

      // PV: out{dt} += mfma(Vt[dt*32+..][kv], P[kv][q]) over kv chunks of 16
      const int nkv = do1 ? 4 : 2;
      __builtin_amdgcn_s_setprio(1);
#pragma unroll 4
      for (int c = 0; c < nkv; ++c) {
        bf16x8 pf = *(const bf16x8*)&Ps[w][ql * 68 + c * 16 + hi5 * 8];
        bf16x8 vf0 = lds_read_sw(Vb[cur], ql, c * 16 + hi5 * 8);
        out0 = __builtin_amdgcn_mfma_f32_32x32x16_bf16(vf0, pf, out0, 0, 0, 0);
        bf16x8 vf1 = lds_read_sw(Vb[cur], 32 + ql, c * 16 + hi5 * 8);
        out1 = __builtin_amdgcn_mfma_f32_32x32x16_bf16(vf1, pf, out1, 0, 0, 0);
      }
      __builtin_amdgcn_s_setprio(0);
    }
    __syncthreads();
  }

  // normalize + store: O[qglob][hoff + dt*32 + 8i + 4*hi5 + {0..3}]
  float rcp = 1.0f / l_r;
  unsigned short* orow = Op + basebs + (size_t)qglob * D_ + hoff;
#pragma unroll
  for (int i = 0; i < 4; ++i) {
    u32x2 o0 = {cvt_pk_bf16(out0[4 * i + 0] * rcp, out0[4 * i + 1] * rcp),
                cvt_pk_bf16(out0[4 * i + 2] * rcp, out0[4 * i + 3] * rcp)};
    *(u32x2*)(orow + 8 * i + 4 * hi5) = o0;
    u32x2 o1 = {cvt_pk_bf16(out1[4 * i + 0] * rcp, out1[4 * i + 1] * rcp),
                cvt_pk_bf16(out1[4 * i + 2] * rcp, out1[4 * i + 3] * rcp)};
    *(u32x2*)(orow + 32 + 8 * i + 4 * hi5) = o1;
  }
}

// ---------------------------- launch ---------------------------------------
extern "C" void kernel_launch(void* const* d_in, const int* in_sizes, int n_in,
                              void* d_out, int out_size, void* d_ws, size_t ws_size,
                              hipStream_t stream) {
  const float* q  = (const float*)d_in[0];
  const float* k  = (const float*)d_in[1];
  const float* v  = (const float*)d_in[2];
  // d_in[3] = causal mask (tril) -- semantics hard-coded in flash_attn
  const float* Wq = (const float*)d_in[4];
  const float* bq = (const float*)d_in[5];
  const float* Wk = (const float*)d_in[6];
  const float* bk = (const float*)d_in[7];
  const float* Wv = (const float*)d_in[8];
  const float* bv = (const float*)d_in[9];
  const float* Wo = (const float*)d_in[10];
  const float* bo = (const float*)d_in[11];

  const int MSD = B_ * S_;     // 4096 rows
  unsigned short* ws = (unsigned short*)d_ws;
  unsigned short* Xq  = ws;
  unsigned short* Xk  = Xq  + (size_t)MSD * D_;
  unsigned short* Xv  = Xk  + (size_t)MSD * D_;
  unsigned short* Wqb = Xv  + (size_t)MSD * D_;
  unsigned short* Wkb = Wqb + (size_t)D_ * D_;
  unsigned short* Wvb = Wkb + (size_t)D_ * D_;
  unsigned short* Wob = Wvb + (size_t)D_ * D_;
  unsigned short* Qp  = Wob + (size_t)D_ * D_;
  unsigned short* Kp  = Qp  + (size_t)MSD * D_;
  unsigned short* Vt  = Kp  + (size_t)MSD * D_;   // V^T per head: [b][h][dk][s]
  unsigned short* At  = Vt  + (size_t)MSD * D_;

  const int n4a = MSD * D_ / 4;   // 1048576
  const int n4w = D_ * D_ / 4;    // 262144
  dim3 g3(n4a / 256, 3);
  cvt3<<<g3, 256, 0, stream>>>(q, k, v, Xq, Xk, Xv);
  dim3 g4(n4w / 256, 4);
  cvt4<<<g4, 256, 0, stream>>>(Wq, Wk, Wv, Wo, Wqb, Wkb, Wvb, Wob);

  dim3 gqkv(MSD / 128, D_ / 128, 3);   // (32, 8, 3) = 768 blocks
  gemm_qkv<<<gqkv, 256, 0, stream>>>(Xq, Xk, Xv, Wqb, Wkb, Wvb,
                                     bq, bk, bv, Qp, Kp, Vt);

  dim3 ga(S_ / 128, H_, B_);           // (16, 16, 2) = 512 blocks
  flash_attn<<<ga, 256, 0, stream>>>(Qp, Kp, Vt, At);

  dim3 go(MSD / 64, D_ / 128);         // (64, 8) = 512 blocks
  gemm_o<<<go, 256, 0, stream>>>(At, Wob, bo, (float*)d_out, MSD, D_, D_);
}